// Round 10
// baseline (107.242 us; speedup 1.0000x reference)
//
#include <hip/hip_runtime.h>
#include <hip/hip_bf16.h>
#include <math.h>

// VectorQuantizer: z [65536 x 64] fp32, codebook [1024 x 64] fp32.
// dist = (||z||^2 - 2 z.e) + ||e||^2, argmin_k, first-occurrence ties.
// Numerics: exact np pairwise sumsq for S/cn; d via f16 split-2 3-pass
// MFMA (err ~1e-8 << absorption bin 7.6e-6); dist compared at 2^9 scale:
// dist9 = (S*2^9 - ds) + cn*2^9  -- pow2 scaling commutes with fp32
// rounding (no under/overflow in range), so ordering/ties are identical
// to the R4-R17 chain; (val, lowest-k) reduce.
//
// R17 post-mortem: hand-asm depth-4 pipeline with counted vmcnt = NULL.
// Latency/issue-structure theories all dead: LDS-DMA/2slot/3slot/pinned/
// asm all ~44us. Wall is proportional to ISSUED WORK at 2 waves/SIMD
// (1536 MFMA x ~20cy/SIMD + ~14us VALU + prologue/epilogue + dep gaps).
// R18 cuts the work: (1) 32x32x16 f16 MFMA -- 12 MFMAs cover 32x32
// (vs 32x16): MFMA count HALVES, per-FLOP cost -15%, groups 64->32
// (half the cnv loads + loop overhead); (2) scale-fold EPI (drop the
// t2 mul, 7->6 ops/elem). ef re-laid out as 8KB per 32-code group.

#define D      64
#define K      1024
#define BLOCK  256

typedef _Float16 half8_t  __attribute__((ext_vector_type(8)));
typedef float    floatx16 __attribute__((ext_vector_type(16)));

// ws layout
#define WS_CN_OFF    0            // float[1024]         (4 KB)
#define WS_EF_OFF    4096         // _Float16[131072]    (256 KB)
// group g (32 codes, 8192 B): slot s = spl*4+ks (spl0=main, spl1=resid)
// at g*8192 + s*1024 bytes; lane l's half8 at +16*l
// (B frag: col = l&31, k = ks*16 + (l>>5)*8 + j).

// numpy pairwise sumsq (n=64): 8 stride-8 accs of fl(x^2), tree combine.
__device__ __forceinline__ float np_sumsq64_p(const float* __restrict__ x) {
    float r[8];
    {
        float4 v0 = *(const float4*)(x);
        float4 v1 = *(const float4*)(x + 4);
        r[0] = __fmul_rn(v0.x, v0.x); r[1] = __fmul_rn(v0.y, v0.y);
        r[2] = __fmul_rn(v0.z, v0.z); r[3] = __fmul_rn(v0.w, v0.w);
        r[4] = __fmul_rn(v1.x, v1.x); r[5] = __fmul_rn(v1.y, v1.y);
        r[6] = __fmul_rn(v1.z, v1.z); r[7] = __fmul_rn(v1.w, v1.w);
    }
#pragma unroll
    for (int i = 8; i < 64; i += 8) {
        float4 v0 = *(const float4*)(x + i);
        float4 v1 = *(const float4*)(x + i + 4);
        r[0] = __fadd_rn(r[0], __fmul_rn(v0.x, v0.x));
        r[1] = __fadd_rn(r[1], __fmul_rn(v0.y, v0.y));
        r[2] = __fadd_rn(r[2], __fmul_rn(v0.z, v0.z));
        r[3] = __fadd_rn(r[3], __fmul_rn(v0.w, v0.w));
        r[4] = __fadd_rn(r[4], __fmul_rn(v1.x, v1.x));
        r[5] = __fadd_rn(r[5], __fmul_rn(v1.y, v1.y));
        r[6] = __fadd_rn(r[6], __fmul_rn(v1.z, v1.z));
        r[7] = __fadd_rn(r[7], __fmul_rn(v1.w, v1.w));
    }
    return __fadd_rn(__fadd_rn(__fadd_rn(r[0], r[1]), __fadd_rn(r[2], r[3])),
                     __fadd_rn(__fadd_rn(r[4], r[5]), __fadd_rn(r[6], r[7])));
}

// ---- precompute: code norms + f16 split-2 B-frags (32x32x16 layout) ----
__global__ void vq_pre(const float* __restrict__ cb, float* __restrict__ cn,
                       _Float16* __restrict__ ef) {
    const int k = blockIdx.x * 64 + threadIdx.x;
    if (k >= K) return;
    cn[k] = np_sumsq64_p(cb + (long)k * D);
    const int g = k >> 5, c32 = k & 31;
#pragma unroll
    for (int ks = 0; ks < 4; ++ks)
#pragma unroll
        for (int hi = 0; hi < 2; ++hi) {
            const float* p = cb + (long)k * D + ks * 16 + hi * 8;
            half8_t h1, h2;
#pragma unroll
            for (int j = 0; j < 8; ++j) {
                float x10 = __fmul_rn(p[j], 1024.0f);        // exact pow2 scale
                _Float16 g1 = (_Float16)x10;
                h1[j] = g1;
                h2[j] = (_Float16)(__fmul_rn(__fsub_rn(x10, (float)g1), 2048.0f));
            }
            // half-offset: group g*4096 + slot*512 + (hi*32 + c32)*8
            const int base = g * 4096 + (hi * 32 + c32) * 8;
            *(half8_t*)(ef + base + ks * 512)       = h1;     // spl0 slot ks
            *(half8_t*)(ef + base + (4 + ks) * 512) = h2;     // spl1 slot 4+ks
        }
}

// ---- main: 128 rows x ALL 1024 codes per 4-wave block; 32x32 MFMA ----
__global__ __launch_bounds__(BLOCK, 2) void vq_main(
    const float* __restrict__ z, const float* __restrict__ cb,
    const _Float16* __restrict__ ef, const float* __restrict__ cn,
    float* __restrict__ zq, float* __restrict__ idx_out) {
    __shared__ __align__(16) float zf[128 * 68];   // 34816 B, +68 stride
    __shared__ float sS[128];                      // S*2^9 (exact pow2)
    __shared__ float sCn[K];                       // cn*2^9 (exact pow2)
    __shared__ int   sBi[128];

    const int tid  = threadIdx.x;
    const int lane = tid & 63;
    const int wv   = tid >> 6;
    const int c32  = lane & 31;
    const int hi   = lane >> 5;
    const long rowbase = (long)blockIdx.x * 128;

    // ---- stage z (coalesced) + scaled code norms ----
    const float4* gz = (const float4*)(z + rowbase * D);
#pragma unroll
    for (int i = 0; i < 8; ++i) {
        int idx4 = i * BLOCK + tid;
        int r = idx4 >> 4, j = idx4 & 15;
        *(float4*)(zf + r * 68 + j * 4) = gz[idx4];
    }
#pragma unroll
    for (int i = 0; i < 4; ++i)
        sCn[i * 256 + tid] = __fmul_rn(cn[i * 256 + tid], 512.0f);
    __syncthreads();

    // row norms (exact np chain), pre-scaled by 2^9 (exact)
    if (tid < 128) sS[tid] = __fmul_rn(np_sumsq64_p(zf + tid * 68), 512.0f);

    // A-frags (32x32x16): wave wv -> rows wv*32 + c32; k = ks*16 + hi*8 + j
    half8_t a1[4], a2[4];
    {
        const int arow = wv * 32 + c32;
#pragma unroll
        for (int ks = 0; ks < 4; ++ks) {
            const float* p = zf + arow * 68 + ks * 16 + hi * 8;
            float4 f0 = *(const float4*)(p);
            float4 f1 = *(const float4*)(p + 4);
            float xs[8] = {f0.x, f0.y, f0.z, f0.w, f1.x, f1.y, f1.z, f1.w};
#pragma unroll
            for (int j = 0; j < 8; ++j) {
                _Float16 h1 = (_Float16)xs[j];
                a1[ks][j] = h1;
                a2[ks][j] =
                    (_Float16)(__fmul_rn(__fsub_rn(xs[j], (float)h1), 2048.0f));
            }
        }
    }
    __syncthreads();   // sS visible to all waves

    // C/D rows for the 16 acc regs: row = (r&3) + 8*(r>>2) + 4*hi
    float myS9[16];
#pragma unroll
    for (int r = 0; r < 16; ++r)
        myS9[r] = sS[wv * 32 + (r & 3) + 8 * (r >> 2) + 4 * hi];

    float bv[16];
    int   bi[16];
#pragma unroll
    for (int r = 0; r < 16; ++r) { bv[r] = INFINITY; bi[r] = 0; }

    const char* eb = (const char*)ef + 16 * lane;
    const floatx16 Z16 = {0.f, 0.f, 0.f, 0.f, 0.f, 0.f, 0.f, 0.f,
                          0.f, 0.f, 0.f, 0.f, 0.f, 0.f, 0.f, 0.f};

// 8 streaming 1KB loads (L2-hot): one 32-code group + scaled cn
#define LOADG(b1_, b2_, cn9_, g_) do {                                        \
        const char* p_ = eb + (size_t)(g_) * 8192;                            \
        b1_[0] = *(const half8_t*)(p_);                                       \
        b1_[1] = *(const half8_t*)(p_ + 1024);                                \
        b1_[2] = *(const half8_t*)(p_ + 2048);                                \
        b1_[3] = *(const half8_t*)(p_ + 3072);                                \
        b2_[0] = *(const half8_t*)(p_ + 4096);                                \
        b2_[1] = *(const half8_t*)(p_ + 5120);                                \
        b2_[2] = *(const half8_t*)(p_ + 6144);                                \
        b2_[3] = *(const half8_t*)(p_ + 7168);                                \
        cn9_ = sCn[(g_) * 32 + c32];                                          \
    } while (0)

// 12 MFMAs (aM: a1*b1 over 4 k-slices; aC: a1*b2 then a2*b1) + EPI:
// ds = fma(aC, 2^-11, aM); dist9 = (S9 - ds) + cn9; strict < keeps
// first occurrence (lowest k via in-lane group order + cross-lane ox<x).
#define COMPUTE(b1_, b2_, cn9_, g_) do {                                      \
        const int kg_ = (g_) * 32 + c32;                                      \
        floatx16 aM, aC;                                                      \
        aM = __builtin_amdgcn_mfma_f32_32x32x16_f16(a1[0], b1_[0], Z16, 0, 0, 0); \
        aC = __builtin_amdgcn_mfma_f32_32x32x16_f16(a1[0], b2_[0], Z16, 0, 0, 0); \
        aM = __builtin_amdgcn_mfma_f32_32x32x16_f16(a1[1], b1_[1], aM, 0, 0, 0);  \
        aC = __builtin_amdgcn_mfma_f32_32x32x16_f16(a1[1], b2_[1], aC, 0, 0, 0);  \
        aM = __builtin_amdgcn_mfma_f32_32x32x16_f16(a1[2], b1_[2], aM, 0, 0, 0);  \
        aC = __builtin_amdgcn_mfma_f32_32x32x16_f16(a1[2], b2_[2], aC, 0, 0, 0);  \
        aM = __builtin_amdgcn_mfma_f32_32x32x16_f16(a1[3], b1_[3], aM, 0, 0, 0);  \
        aC = __builtin_amdgcn_mfma_f32_32x32x16_f16(a1[3], b2_[3], aC, 0, 0, 0);  \
        aC = __builtin_amdgcn_mfma_f32_32x32x16_f16(a2[0], b1_[0], aC, 0, 0, 0);  \
        aC = __builtin_amdgcn_mfma_f32_32x32x16_f16(a2[1], b1_[1], aC, 0, 0, 0);  \
        aC = __builtin_amdgcn_mfma_f32_32x32x16_f16(a2[2], b1_[2], aC, 0, 0, 0);  \
        aC = __builtin_amdgcn_mfma_f32_32x32x16_f16(a2[3], b1_[3], aC, 0, 0, 0);  \
        _Pragma("unroll")                                                     \
        for (int r = 0; r < 16; ++r) {                                        \
            float ds = fmaf(aC[r], 0x1p-11f, aM[r]);                          \
            float d9 = __fadd_rn(__fsub_rn(myS9[r], ds), cn9_);               \
            if (d9 < bv[r]) { bv[r] = d9; bi[r] = kg_; }                      \
        }                                                                     \
    } while (0)

    // 2-slot rotation over 32 groups; no barriers, waves free-run
    half8_t b1A[4], b2A[4], b1B[4], b2B[4];
    float cnA, cnB;
    LOADG(b1A, b2A, cnA, 0);
    for (int g = 0; g < 32; g += 2) {
        LOADG(b1B, b2B, cnB, g + 1);
        COMPUTE(b1A, b2A, cnA, g);
        if (g + 2 < 32) LOADG(b1A, b2A, cnA, g + 2);
        COMPUTE(b1B, b2B, cnB, g + 1);
    }

#undef LOADG
#undef COMPUTE

    // reduce over 32 code-columns (within each 32-lane half);
    // (val, lowest index) = first occurrence
#pragma unroll
    for (int r = 0; r < 16; ++r) {
        float v = bv[r];
        int   x = bi[r];
#pragma unroll
        for (int off = 1; off <= 16; off <<= 1) {
            float ov = __shfl_xor(v, off);
            int   ox = __shfl_xor(x, off);
            if (ov < v || (ov == v && ox < x)) { v = ov; x = ox; }
        }
        if (c32 == 0) {
            const int row = wv * 32 + (r & 3) + 8 * (r >> 2) + 4 * hi;
            sBi[row] = x;
            idx_out[rowbase + row] = (float)x;
        }
    }
    __syncthreads();

    // ---- zq gather: zq[row] = cb[bi[row]] (cb L2-hot, coalesced writes) ----
    const float4* cb4 = (const float4*)cb;
    float4* zq4 = (float4*)(zq + rowbase * D);
#pragma unroll
    for (int i = 0; i < 8; ++i) {
        int idx4 = i * BLOCK + tid;
        int r = idx4 >> 4, j = idx4 & 15;
        zq4[idx4] = cb4[(long)sBi[r] * 16 + j];
    }
}

extern "C" void kernel_launch(void* const* d_in, const int* in_sizes, int n_in,
                              void* d_out, int out_size, void* d_ws, size_t ws_size,
                              hipStream_t stream) {
    const float* z  = (const float*)d_in[0];
    const float* cb = (const float*)d_in[1];

    const int n_rows = in_sizes[0] / D;                 // 65536
    float* zq      = (float*)d_out;
    float* idx_out = zq + (long)n_rows * D;

    float*    ws_cn = (float*)((char*)d_ws + WS_CN_OFF);
    _Float16* ws_ef = (_Float16*)((char*)d_ws + WS_EF_OFF);

    vq_pre<<<K / 64, 64, 0, stream>>>(cb, ws_cn, ws_ef);
    vq_main<<<n_rows / 128, BLOCK, 0, stream>>>(z, cb, ws_ef, ws_cn, zq, idx_out);
}